// Round 1
// baseline (3064.643 us; speedup 1.0000x reference)
//
#include <hip/hip_runtime.h>
#include <hip/hip_bf16.h>

#define T_TOK 4096
#define HDIM 4096
#define IDIM 14336
#define RR 159
#define NE 8
#define ROWCAP 8320  // 8192 + 128 pad rows for partial-tile staging reads

typedef __attribute__((ext_vector_type(8))) short bf16x8;
typedef __attribute__((ext_vector_type(4))) float f32x4;

__device__ __forceinline__ unsigned short f2b(float f) {
  unsigned int x = __builtin_bit_cast(unsigned int, f);
  x += 0x7fffu + ((x >> 16) & 1u);
  return (unsigned short)(x >> 16);
}

// ---------------- router: exact fp32 ----------------
__global__ void k_router(const float* __restrict__ x, const float* __restrict__ gw,
                         float* __restrict__ logits_out, int* __restrict__ counts,
                         int* __restrict__ sel, float* __restrict__ rw) {
  const int t = blockIdx.x;
  const int lane = threadIdx.x;  // blockDim = 64 (one wave)
  float acc[8];
#pragma unroll
  for (int e = 0; e < 8; ++e) acc[e] = 0.f;
  const float4* xv = (const float4*)(x + (long)t * HDIM);
  for (int i = 0; i < 16; ++i) {
    const int c = lane + 64 * i;
    const float4 xc = xv[c];
#pragma unroll
    for (int e = 0; e < 8; ++e) {
      const float4 g = ((const float4*)(gw + (long)e * HDIM))[c];
      acc[e] += xc.x * g.x + xc.y * g.y + xc.z * g.z + xc.w * g.w;
    }
  }
#pragma unroll
  for (int e = 0; e < 8; ++e) {
    float v = acc[e];
#pragma unroll
    for (int o = 32; o > 0; o >>= 1) v += __shfl_xor(v, o, 64);
    acc[e] = v;
  }
  if (lane == 0) {
#pragma unroll
    for (int e = 0; e < 8; ++e) logits_out[(long)t * 8 + e] = acc[e];
    int i1 = 0; float l1 = acc[0];
#pragma unroll
    for (int e = 1; e < 8; ++e) if (acc[e] > l1) { l1 = acc[e]; i1 = e; }
    int i2 = -1; float l2 = -3.4e38f;
#pragma unroll
    for (int e = 0; e < 8; ++e) if (e != i1 && acc[e] > l2) { l2 = acc[e]; i2 = e; }
    const float p2 = expf(l2 - l1);  // top-2 renorm == softmax ratio, denom cancels
    sel[2 * t] = i1; sel[2 * t + 1] = i2;
    rw[2 * t] = 1.f / (1.f + p2);
    rw[2 * t + 1] = p2 / (1.f + p2);
    atomicAdd(&counts[i1], 1);
    atomicAdd(&counts[i2], 1);
  }
}

__global__ void k_offsets(const int* __restrict__ counts, int* __restrict__ seg_off,
                          int* __restrict__ cursors) {
  if (threadIdx.x == 0) {
    int s = 0;
    for (int e = 0; e < 8; ++e) { seg_off[e] = s; s += counts[e]; }
    seg_off[8] = s;
  }
  if (threadIdx.x < 8) cursors[threadIdx.x] = 0;
}

__global__ void k_scatter(const int* __restrict__ sel, const float* __restrict__ rw,
                          const int* __restrict__ seg_off, int* __restrict__ cursors,
                          int* __restrict__ tok_idx, float* __restrict__ tok_w) {
  const int t = blockIdx.x * 256 + threadIdx.x;
  if (t >= T_TOK) return;
#pragma unroll
  for (int s = 0; s < 2; ++s) {
    const int e = sel[2 * t + s];
    const int p = atomicAdd(&cursors[e], 1);
    const int g = seg_off[e] + p;
    tok_idx[g] = t;
    tok_w[g] = rw[2 * t + s];
  }
}

// gather x rows (token order -> segmented order), fp32 -> bf16
__global__ void k_gather(const float* __restrict__ x, const int* __restrict__ tok_idx,
                         unsigned short* __restrict__ xg) {
  const int row = blockIdx.x;  // 8192 rows, all filled by scatter (sum counts == 8192)
  const int tok = tok_idx[row];
  const float4* src = (const float4*)(x + (long)tok * HDIM);
#pragma unroll
  for (int i = 0; i < 4; ++i) {
    const int c = threadIdx.x + 256 * i;
    const float4 v = src[c];
    ushort4 o;
    o.x = f2b(v.x); o.y = f2b(v.y); o.z = f2b(v.z); o.w = f2b(v.w);
    *(ushort4*)&xg[(long)row * HDIM + c * 4] = o;
  }
}

// ------------- weight preconversion: fp32 -> zero-padded bf16 -------------
// WA: [E][640][4096], n = m*160+r, m in {w1v,v1,w3v,v3}; row r==159 zeroed
__global__ void k_convWA(const float* __restrict__ w1v, const float* __restrict__ v1,
                         const float* __restrict__ w3v, const float* __restrict__ v3,
                         unsigned short* __restrict__ WA) {
  const long N = (long)NE * 640 * HDIM;
  for (long d = (long)blockIdx.x * 256 + threadIdx.x; d < N; d += (long)gridDim.x * 256) {
    const int k = (int)(d & (HDIM - 1));
    const long q = d >> 12;
    const int n = (int)(q % 640);
    const int e = (int)(q / 640);
    const int m = n / 160, r = n - m * 160;
    const float* s = (m == 0) ? w1v : (m == 1) ? v1 : (m == 2) ? w3v : v3;
    const float v = (r < RR) ? s[((long)e * RR + r) * HDIM + k] : 0.f;
    WA[d] = f2b(v);
  }
}

// WB: [2][E][IDIM][320]; kk<160: w1u/w3u (pad 159), kk>=160: u1/u3 (pad 319)
__global__ void k_convWB(const float* __restrict__ w1u, const float* __restrict__ u1,
                         const float* __restrict__ w3u, const float* __restrict__ u3,
                         unsigned short* __restrict__ WB) {
  const long N = (long)2 * NE * IDIM * 320;
  for (long d = (long)blockIdx.x * 256 + threadIdx.x; d < N; d += (long)gridDim.x * 256) {
    const int kk = (int)(d % 320);
    const long q = d / 320;
    const int n = (int)(q % IDIM);
    const long q2 = q / IDIM;
    const int e = (int)(q2 & 7);
    const int s = (int)(q2 >> 3);
    const float* W = s ? w3u : w1u;
    const float* U = s ? u3 : u1;
    float v = 0.f;
    if (kk < 160) { if (kk < RR) v = W[((long)e * IDIM + n) * RR + kk]; }
    else { const int r = kk - 160; if (r < RR) v = U[((long)e * IDIM + n) * RR + r]; }
    WB[d] = f2b(v);
  }
}

// WC: [E][320][IDIM]; rows 0..158 w2v, 160..318 v2, rows 159/319 zero
__global__ void k_convWC(const float* __restrict__ w2v, const float* __restrict__ v2,
                         unsigned short* __restrict__ WC) {
  const long N = (long)NE * 320 * IDIM;
  for (long d = (long)blockIdx.x * 256 + threadIdx.x; d < N; d += (long)gridDim.x * 256) {
    const int k = (int)(d % IDIM);
    const long q = d / IDIM;
    const int rr = (int)(q % 320);
    const int e = (int)(q / 320);
    float v = 0.f;
    if (rr < 160) { if (rr < RR) v = w2v[((long)e * RR + rr) * IDIM + k]; }
    else { const int r = rr - 160; if (r < RR) v = v2[((long)e * RR + r) * IDIM + k]; }
    WC[d] = f2b(v);
  }
}

// WD: [E][HDIM][320]; kk<160: w2u, kk>=160: u2
__global__ void k_convWD(const float* __restrict__ w2u, const float* __restrict__ u2,
                         unsigned short* __restrict__ WD) {
  const long N = (long)NE * HDIM * 320;
  for (long d = (long)blockIdx.x * 256 + threadIdx.x; d < N; d += (long)gridDim.x * 256) {
    const int kk = (int)(d % 320);
    const long q = d / 320;
    const int n = (int)(q % HDIM);
    const int e = (int)(q / HDIM);
    float v = 0.f;
    if (kk < 160) { if (kk < RR) v = w2u[((long)e * HDIM + n) * RR + kk]; }
    else { const int r = kk - 160; if (r < RR) v = u2[((long)e * HDIM + n) * RR + r]; }
    WD[d] = f2b(v);
  }
}

__global__ void k_cvt_hr(const float* __restrict__ hrf, unsigned short* __restrict__ hrb) {
  const long N = (long)ROWCAP * 320;
  for (long d = (long)blockIdx.x * 256 + threadIdx.x; d < N; d += (long)gridDim.x * 256)
    hrb[d] = f2b(hrf[d]);
}

// ---------------- generic MFMA GEMM ----------------
// C[rows(segmented), BN-tile] = A[rows][KB] * B[e][NB][KB]^T  (both bf16, K-major)
// EPI: 0=store bf16  1=silu(acc)*acc2 store bf16 (DUAL)  2=atomicAdd fp32  3=scatter w*acc
template <int NI, bool DUAL, int EPI, int KSPLIT>
__global__ __launch_bounds__(256, 2) void k_gemm(
    const unsigned short* __restrict__ A, int lda, int koffA2,
    const unsigned short* __restrict__ B0, const unsigned short* __restrict__ B1,
    long strideB, int NB, int KB,
    unsigned short* __restrict__ out_b, float* __restrict__ out_f, int ldo, int NOUT,
    const int* __restrict__ seg_off, const int* __restrict__ counts,
    const int* __restrict__ tok_idx, const float* __restrict__ tok_w,
    float* __restrict__ final_out) {
  constexpr int BN = 32 * NI;
  const int e = blockIdx.z / KSPLIT;
  const int ks = blockIdx.z % KSPLIT;
  const int cnt = counts[e];
  const int tm = blockIdx.x;
  if (tm * 128 >= cnt) return;
  const long m0 = (long)seg_off[e] + (long)tm * 128;
  const int n0 = blockIdx.y * BN;
  const int kchunk = KB / KSPLIT;
  const int kbeg = ks * kchunk;
  const unsigned short* Be0 = B0 + (long)e * strideB;
  const unsigned short* Be1 = DUAL ? B1 + (long)e * strideB : (const unsigned short*)0;

  __shared__ __align__(16) unsigned short As[128 * 40];
  __shared__ __align__(16) unsigned short Bs[BN * 40];
  __shared__ __align__(16) unsigned short Au[DUAL ? 128 * 40 : 8];
  __shared__ __align__(16) unsigned short Bu[DUAL ? BN * 40 : 8];

  const int tid = threadIdx.x;
  const int lane = tid & 63;
  const int wave = tid >> 6;
  const int wm = wave & 1, wn = wave >> 1;

  f32x4 acc[4][NI];
  f32x4 acc2[DUAL ? 4 : 1][DUAL ? NI : 1];
#pragma unroll
  for (int mi = 0; mi < 4; ++mi)
#pragma unroll
    for (int ni = 0; ni < NI; ++ni) {
      acc[mi][ni] = f32x4{0.f, 0.f, 0.f, 0.f};
      if constexpr (DUAL) acc2[mi][ni] = f32x4{0.f, 0.f, 0.f, 0.f};
    }

  for (int k0 = kbeg; k0 < kbeg + kchunk; k0 += 32) {
    __syncthreads();
#pragma unroll
    for (int i = 0; i < 2; ++i) {  // A tile: 128x32 = 512 chunks of 8 bf16
      const int c = tid + 256 * i;
      const int row = c >> 2, kc = (c & 3) << 3;
      *(uint4*)&As[row * 40 + kc] = *(const uint4*)(A + (m0 + row) * (long)lda + (k0 + kc));
      if constexpr (DUAL)
        *(uint4*)&Au[row * 40 + kc] =
            *(const uint4*)(A + (m0 + row) * (long)lda + (koffA2 + k0 + kc));
    }
#pragma unroll
    for (int i = 0; i < BN / 64; ++i) {  // B tile: BNx32
      const int c = tid + 256 * i;
      const int row = c >> 2, kc = (c & 3) << 3;
      int nb = n0 + row;
      nb = nb < NB ? nb : NB - 1;  // clamp partial-N staging (stage C tile 2)
      *(uint4*)&Bs[row * 40 + kc] = *(const uint4*)(Be0 + (long)nb * KB + (k0 + kc));
      if constexpr (DUAL)
        *(uint4*)&Bu[row * 40 + kc] = *(const uint4*)(Be1 + (long)nb * KB + (k0 + kc));
    }
    __syncthreads();

    const int kk = (lane >> 4) << 3;
    const int fr = lane & 15;
    bf16x8 af[4], bfr[NI];
#pragma unroll
    for (int mi = 0; mi < 4; ++mi)
      af[mi] = *(const bf16x8*)&As[(wm * 64 + mi * 16 + fr) * 40 + kk];
#pragma unroll
    for (int ni = 0; ni < NI; ++ni)
      bfr[ni] = *(const bf16x8*)&Bs[(wn * (NI * 16) + ni * 16 + fr) * 40 + kk];
#pragma unroll
    for (int mi = 0; mi < 4; ++mi)
#pragma unroll
      for (int ni = 0; ni < NI; ++ni)
        acc[mi][ni] =
            __builtin_amdgcn_mfma_f32_16x16x32_bf16(af[mi], bfr[ni], acc[mi][ni], 0, 0, 0);
    if constexpr (DUAL) {
      bf16x8 au[4], bu[NI];
#pragma unroll
      for (int mi = 0; mi < 4; ++mi)
        au[mi] = *(const bf16x8*)&Au[(wm * 64 + mi * 16 + fr) * 40 + kk];
#pragma unroll
      for (int ni = 0; ni < NI; ++ni)
        bu[ni] = *(const bf16x8*)&Bu[(wn * (NI * 16) + ni * 16 + fr) * 40 + kk];
#pragma unroll
      for (int mi = 0; mi < 4; ++mi)
#pragma unroll
        for (int ni = 0; ni < NI; ++ni)
          acc2[mi][ni] =
              __builtin_amdgcn_mfma_f32_16x16x32_bf16(au[mi], bu[ni], acc2[mi][ni], 0, 0, 0);
    }
  }

  const int rowlim = cnt - tm * 128;
  const int fcol = lane & 15;
  const int rb = (lane >> 4) << 2;
#pragma unroll
  for (int mi = 0; mi < 4; ++mi) {
#pragma unroll
    for (int ni = 0; ni < NI; ++ni) {
      const int col = n0 + wn * (NI * 16) + ni * 16 + fcol;
#pragma unroll
      for (int j = 0; j < 4; ++j) {
        const int rl = wm * 64 + mi * 16 + rb + j;
        if (rl >= rowlim || col >= NOUT) continue;
        const long grow = m0 + rl;
        const float v = acc[mi][ni][j];
        if constexpr (EPI == 0) {
          out_b[grow * (long)ldo + col] = f2b(v);
        } else if constexpr (EPI == 1) {
          const float u = acc2[mi][ni][j];
          const float hv = v * u / (1.f + __expf(-v));  // silu(gate)*up
          out_b[grow * (long)ldo + col] = f2b(hv);
        } else if constexpr (EPI == 2) {
          atomicAdd(out_f + grow * (long)ldo + col, v);
        } else {
          const int t = tok_idx[grow];
          const float w = tok_w[grow];
          atomicAdd(final_out + (long)t * HDIM + col, v * w);
        }
      }
    }
  }
}

// ---------------- launch ----------------
extern "C" void kernel_launch(void* const* d_in, const int* in_sizes, int n_in,
                              void* d_out, int out_size, void* d_ws, size_t ws_size,
                              hipStream_t stream) {
  const float* x    = (const float*)d_in[0];
  const float* gw   = (const float*)d_in[1];
  const float* w1u  = (const float*)d_in[2];
  const float* w1v  = (const float*)d_in[3];
  const float* w2u  = (const float*)d_in[4];
  const float* w2v  = (const float*)d_in[5];
  const float* w3u  = (const float*)d_in[6];
  const float* w3v  = (const float*)d_in[7];
  const float* u1   = (const float*)d_in[8];
  const float* v1   = (const float*)d_in[9];
  const float* u2   = (const float*)d_in[10];
  const float* v2   = (const float*)d_in[11];
  const float* u3   = (const float*)d_in[12];
  const float* v3   = (const float*)d_in[13];

  float* out_final  = (float*)d_out;                       // [T, H]
  float* out_logits = out_final + (size_t)T_TOK * HDIM;    // [T, E]

  char* W = (char*)d_ws;
  size_t o = 0;
  auto alloc = [&](size_t bytes) {
    size_t r = o;
    o = (o + bytes + 255) & ~(size_t)255;
    return r;
  };
  int*   counts  = (int*)(W + alloc(8 * 4));
  int*   cursors = (int*)(W + alloc(8 * 4));
  int*   seg_off = (int*)(W + alloc(16 * 4));
  int*   sel     = (int*)(W + alloc((size_t)2 * T_TOK * 4));
  float* rw      = (float*)(W + alloc((size_t)2 * T_TOK * 4));
  int*   tok_idx = (int*)(W + alloc((size_t)ROWCAP * 4));
  float* tok_w   = (float*)(W + alloc((size_t)ROWCAP * 4));
  unsigned short* WA  = (unsigned short*)(W + alloc((size_t)NE * 640 * HDIM * 2));
  unsigned short* WB  = (unsigned short*)(W + alloc((size_t)2 * NE * IDIM * 320 * 2));
  unsigned short* WC  = (unsigned short*)(W + alloc((size_t)NE * 320 * IDIM * 2));
  unsigned short* WD  = (unsigned short*)(W + alloc((size_t)NE * HDIM * 320 * 2));
  unsigned short* xg  = (unsigned short*)(W + alloc((size_t)ROWCAP * HDIM * 2));
  unsigned short* xr  = (unsigned short*)(W + alloc((size_t)ROWCAP * 640 * 2));
  unsigned short* hb  = (unsigned short*)(W + alloc((size_t)ROWCAP * IDIM * 2));
  float*          hrf = (float*)(W + alloc((size_t)ROWCAP * 320 * 4));
  unsigned short* hrb = (unsigned short*)(W + alloc((size_t)ROWCAP * 320 * 2));
  (void)ws_size; (void)in_sizes; (void)n_in; (void)out_size;

  hipMemsetAsync(counts, 0, 8 * 4, stream);
  hipMemsetAsync(tok_idx, 0, (size_t)ROWCAP * 4, stream);
  hipMemsetAsync(tok_w, 0, (size_t)ROWCAP * 4, stream);
  hipMemsetAsync(hrf, 0, (size_t)ROWCAP * 320 * 4, stream);
  hipMemsetAsync(d_out, 0, (size_t)T_TOK * HDIM * 4, stream);  // final zeroed; logits fully written

  k_router<<<T_TOK, 64, 0, stream>>>(x, gw, out_logits, counts, sel, rw);
  k_offsets<<<1, 64, 0, stream>>>(counts, seg_off, cursors);
  k_scatter<<<T_TOK / 256, 256, 0, stream>>>(sel, rw, seg_off, cursors, tok_idx, tok_w);

  k_convWA<<<2048, 256, 0, stream>>>(w1v, v1, w3v, v3, WA);
  k_convWB<<<8192, 256, 0, stream>>>(w1u, u1, w3u, u3, WB);
  k_convWC<<<4096, 256, 0, stream>>>(w2v, v2, WC);
  k_convWD<<<1024, 256, 0, stream>>>(w2u, u2, WD);
  k_gather<<<8192, 256, 0, stream>>>(x, tok_idx, xg);

  // Stage A: xr[rows,640] = xg[rows,4096] @ WA^T   (4 V-projections at once)
  k_gemm<4, false, 0, 1><<<dim3(32, 5, 8), 256, 0, stream>>>(
      xg, HDIM, 0, WA, (const unsigned short*)0, (long)640 * HDIM, 640, HDIM,
      xr, (float*)0, 640, 640, seg_off, counts, (const int*)0, (const float*)0, (float*)0);

  // Stage B: h = silu(gate)*up ; gate/up are K=320 GEMMs over stacked [Wu;U] weights
  k_gemm<2, true, 1, 1><<<dim3(32, 224, 8), 256, 0, stream>>>(
      xr, 640, 320, WB, WB + (size_t)NE * IDIM * 320, (long)IDIM * 320, IDIM, 320,
      hb, (float*)0, IDIM, IDIM, seg_off, counts, (const int*)0, (const float*)0, (float*)0);

  // Stage C: hr[rows,320] = h @ WC^T, K=14336 split 4 ways, fp32 atomic partials
  k_gemm<4, false, 2, 4><<<dim3(32, 3, 32), 256, 0, stream>>>(
      hb, IDIM, 0, WC, (const unsigned short*)0, (long)320 * IDIM, 320, IDIM,
      (unsigned short*)0, hrf, 320, 320, seg_off, counts, (const int*)0, (const float*)0,
      (float*)0);

  k_cvt_hr<<<1024, 256, 0, stream>>>(hrf, hrb);

  // Stage D: out = (hr @ WD^T) * w_tok, scatter-atomicAdd into final
  k_gemm<4, false, 3, 1><<<dim3(32, 32, 8), 256, 0, stream>>>(
      hrb, 320, 0, WD, (const unsigned short*)0, (long)HDIM * 320, HDIM, 320,
      (unsigned short*)0, (float*)0, 0, HDIM, seg_off, counts, tok_idx, tok_w, out_final);
}

// Round 2
// 1547.319 us; speedup vs baseline: 1.9806x; 1.9806x over previous
//
#include <hip/hip_runtime.h>
#include <hip/hip_bf16.h>

#define T_TOK 4096
#define HDIM 4096
#define IDIM 14336
#define RR 159
#define NE 8
#define ROWCAP 8320  // 8192 slots + 128 pad rows for tile over-reads

typedef unsigned short u16;
typedef __attribute__((ext_vector_type(8))) short bf16x8;
typedef __attribute__((ext_vector_type(4))) float f32x4;

__device__ __forceinline__ u16 f2b(float f) {
  unsigned int x = __builtin_bit_cast(unsigned int, f);
  x += 0x7fffu + ((x >> 16) & 1u);
  return (u16)(x >> 16);
}
__device__ __forceinline__ float b2f(u16 x) {
  unsigned int u = ((unsigned int)x) << 16;
  return __builtin_bit_cast(float, u);
}

// async global->LDS, 16B per lane; LDS dest wave-uniform base + lane*16
__device__ __forceinline__ void gload16(const void* g, void* s) {
  __builtin_amdgcn_global_load_lds(
      (const __attribute__((address_space(1))) unsigned int*)g,
      (__attribute__((address_space(3))) unsigned int*)s, 16, 0, 0);
}

// ---------------- router: exact fp32 ----------------
__global__ void k_router(const float* __restrict__ x, const float* __restrict__ gw,
                         float* __restrict__ logits_out, int* __restrict__ counts,
                         int* __restrict__ sel, float* __restrict__ rw) {
  const int t = blockIdx.x;
  const int lane = threadIdx.x;  // 64
  float acc[8];
#pragma unroll
  for (int e = 0; e < 8; ++e) acc[e] = 0.f;
  const float4* xv = (const float4*)(x + (long)t * HDIM);
  for (int i = 0; i < 16; ++i) {
    const int c = lane + 64 * i;
    const float4 xc = xv[c];
#pragma unroll
    for (int e = 0; e < 8; ++e) {
      const float4 g = ((const float4*)(gw + (long)e * HDIM))[c];
      acc[e] += xc.x * g.x + xc.y * g.y + xc.z * g.z + xc.w * g.w;
    }
  }
#pragma unroll
  for (int e = 0; e < 8; ++e) {
    float v = acc[e];
#pragma unroll
    for (int o = 32; o > 0; o >>= 1) v += __shfl_xor(v, o, 64);
    acc[e] = v;
  }
  if (lane == 0) {
#pragma unroll
    for (int e = 0; e < 8; ++e) logits_out[(long)t * 8 + e] = acc[e];
    int i1 = 0; float l1 = acc[0];
#pragma unroll
    for (int e = 1; e < 8; ++e) if (acc[e] > l1) { l1 = acc[e]; i1 = e; }
    int i2 = -1; float l2 = -3.4e38f;
#pragma unroll
    for (int e = 0; e < 8; ++e) if (e != i1 && acc[e] > l2) { l2 = acc[e]; i2 = e; }
    const float p2 = expf(l2 - l1);
    sel[2 * t] = i1; sel[2 * t + 1] = i2;
    rw[2 * t] = 1.f / (1.f + p2);
    rw[2 * t + 1] = p2 / (1.f + p2);
    atomicAdd(&counts[i1], 1);
    atomicAdd(&counts[i2], 1);
  }
}

__global__ void k_offsets(const int* __restrict__ counts, int* __restrict__ seg_off,
                          int* __restrict__ cursors) {
  if (threadIdx.x == 0) {
    int s = 0;
    for (int e = 0; e < 8; ++e) { seg_off[e] = s; s += counts[e]; }
    seg_off[8] = s;
  }
  if (threadIdx.x < 8) cursors[threadIdx.x] = 0;
}

__global__ void k_scatter(const int* __restrict__ sel, const float* __restrict__ rw,
                          const int* __restrict__ seg_off, int* __restrict__ cursors,
                          int* __restrict__ tok_idx, float* __restrict__ tok_w,
                          int* __restrict__ inv) {
  const int t = blockIdx.x * 256 + threadIdx.x;
  if (t >= T_TOK) return;
#pragma unroll
  for (int s = 0; s < 2; ++s) {
    const int e = sel[2 * t + s];
    const int p = atomicAdd(&cursors[e], 1);
    const int g = seg_off[e] + p;
    tok_idx[g] = t;
    tok_w[g] = rw[2 * t + s];
    inv[2 * t + s] = g;
  }
}

__global__ void k_gather(const float* __restrict__ x, const int* __restrict__ tok_idx,
                         u16* __restrict__ xg) {
  const int row = blockIdx.x;  // 8192
  const int tok = tok_idx[row];
  const float4* src = (const float4*)(x + (long)tok * HDIM);
#pragma unroll
  for (int i = 0; i < 4; ++i) {
    const int c = threadIdx.x + 256 * i;
    const float4 v = src[c];
    ushort4 o;
    o.x = f2b(v.x); o.y = f2b(v.y); o.z = f2b(v.z); o.w = f2b(v.w);
    *(ushort4*)&xg[(long)row * HDIM + c * 4] = o;
  }
}

// ------------- weight preconversion (no per-element div/mod) -------------
// WA: [E][640][4096]; n = m*160+r, m in {w1v,v1,w3v,v3}; r==159 zero row
__global__ void k_convWA(const float* __restrict__ w1v, const float* __restrict__ v1,
                         const float* __restrict__ w3v, const float* __restrict__ v3,
                         u16* __restrict__ WA) {
  const int r = blockIdx.x, e = blockIdx.y;
  const int m = r / 160, rr = r - m * 160;
  const float* s = (m == 0) ? w1v : (m == 1) ? v1 : (m == 2) ? w3v : v3;
  u16* dst = WA + ((long)e * 640 + r) * HDIM;
  if (rr == RR) {
#pragma unroll
    for (int j = 0; j < 4; ++j)
      *(ushort4*)&dst[(threadIdx.x + j * 256) * 4] = ushort4{0, 0, 0, 0};
    return;
  }
  const float4* src = (const float4*)(s + ((long)e * RR + rr) * HDIM);
#pragma unroll
  for (int j = 0; j < 4; ++j) {
    const int c = threadIdx.x + j * 256;
    const float4 v = src[c];
    ushort4 o; o.x = f2b(v.x); o.y = f2b(v.y); o.z = f2b(v.z); o.w = f2b(v.w);
    *(ushort4*)&dst[c * 4] = o;
  }
}

// WB: [2][E][IDIM][320]; kk<160: w1u/w3u row, kk>=160: u1/u3 row (159,319 zero)
__global__ void k_convWB(const float* __restrict__ w1u, const float* __restrict__ u1,
                         const float* __restrict__ w3u, const float* __restrict__ u3,
                         u16* __restrict__ WB) {
  const int n = blockIdx.x * 4 + (threadIdx.x >> 6);
  const int t = threadIdx.x & 63;
  const int s = blockIdx.y >> 3, e = blockIdx.y & 7;
  const float* W = s ? w3u : w1u;
  const float* U = s ? u3 : u1;
  const long base = ((long)e * IDIM + n) * RR;
  u16* dst = WB + (((long)(s * 8 + e) * IDIM + n) * 320);
#pragma unroll
  for (int j = 0; j < 5; ++j) {
    const int kk = t + 64 * j;
    float v = 0.f;
    if (kk < 160) { if (kk < RR) v = W[base + kk]; }
    else { const int r = kk - 160; if (r < RR) v = U[base + r]; }
    dst[kk] = f2b(v);
  }
}

// WC: [E][320][IDIM]; rows 0..158 w2v, 160..318 v2; 159/319 zero
__global__ void k_convWC(const float* __restrict__ w2v, const float* __restrict__ v2,
                         u16* __restrict__ WC) {
  const int rr = blockIdx.x, e = blockIdx.y;
  u16* dst = WC + ((long)e * 320 + rr) * IDIM;
  const float* src = 0;
  if (rr < 160) { if (rr < RR) src = w2v + ((long)e * RR + rr) * IDIM; }
  else { const int r = rr - 160; if (r < RR) src = v2 + ((long)e * RR + r) * IDIM; }
  if (!src) {
#pragma unroll
    for (int j = 0; j < 14; ++j)
      *(ushort4*)&dst[(threadIdx.x + j * 256) * 4] = ushort4{0, 0, 0, 0};
    return;
  }
#pragma unroll
  for (int j = 0; j < 14; ++j) {
    const int c = threadIdx.x + j * 256;
    const float4 v = ((const float4*)src)[c];
    ushort4 o; o.x = f2b(v.x); o.y = f2b(v.y); o.z = f2b(v.z); o.w = f2b(v.w);
    *(ushort4*)&dst[c * 4] = o;
  }
}

// WD: [E][HDIM][320]; kk<160: w2u, kk>=160: u2
__global__ void k_convWD(const float* __restrict__ w2u, const float* __restrict__ u2,
                         u16* __restrict__ WD) {
  const int n = blockIdx.x * 4 + (threadIdx.x >> 6);
  const int t = threadIdx.x & 63;
  const int e = blockIdx.y;
  const long base = ((long)e * HDIM + n) * RR;
  u16* dst = WD + ((long)e * HDIM + n) * 320;
#pragma unroll
  for (int j = 0; j < 5; ++j) {
    const int kk = t + 64 * j;
    float v = 0.f;
    if (kk < 160) { if (kk < RR) v = w2u[base + kk]; }
    else { const int r = kk - 160; if (r < RR) v = u2[base + r]; }
    dst[kk] = f2b(v);
  }
}

// ---------------- m97-class MFMA GEMM, BK=64, swizzled global_load_lds ----------------
// C[rows(segmented), BN] = A[rows][KB] * B[e][NB][KB]^T
// EPI: 0=store bf16  1=silu(acc)*acc2 -> bf16 (DUAL)  2=fp32 partial store (KSPLIT)
template <int NI, bool DUAL, int EPI, int KSPLIT>
__global__ __launch_bounds__(256, 2) void k_gemm(
    const u16* __restrict__ A, int lda, int koffA2,
    const u16* __restrict__ B0, const u16* __restrict__ B1, long strideB,
    int NB, int KB,
    u16* __restrict__ out_b, float* __restrict__ out_f, int ldo, int NOUT,
    const int* __restrict__ seg_off, const int* __restrict__ counts) {
  constexpr int BN = 32 * NI;
  constexpr int AIT = 4;        // 128 rows * 8 chunks / 256 threads
  constexpr int BIT = BN / 32;  // BN rows * 8 chunks / 256 threads
  const int e = blockIdx.z / KSPLIT;
  const int ks = blockIdx.z % KSPLIT;
  const int cnt = counts[e];
  const int n0 = blockIdx.x * BN;  // x = N-tile so B-panel sharers land on one XCD
  const int kchunk = KB / KSPLIT;
  const int kbeg = ks * kchunk;
  const u16* Be0 = B0 + (long)e * strideB;
  const u16* Be1 = DUAL ? B1 + (long)e * strideB : B0;

  __shared__ __align__(16) u16 As[128 * 64];
  __shared__ __align__(16) u16 Bs[BN * 64];
  __shared__ __align__(16) u16 Au[DUAL ? 128 * 64 : 8];
  __shared__ __align__(16) u16 Bu[DUAL ? BN * 64 : 8];

  const int tid = threadIdx.x;
  const int lane = tid & 63;
  const int wm = (tid >> 6) & 1;
  const int wn = tid >> 7;
  const int g = lane >> 4;
  const int fr = lane & 15;

  // staging offsets: LDS chunk p = r*8+c holds global chunk (r, c ^ (r&7))
  int aoff[AIT], boff[BIT], ldsA[AIT], ldsB[BIT];
#pragma unroll
  for (int i = 0; i < AIT; ++i) {
    const int p = i * 256 + tid;
    const int r = p >> 3, c = p & 7;
    aoff[i] = r * lda + ((c ^ (r & 7)) << 3);
    ldsA[i] = (i * 256 + (tid & ~63)) * 8;
  }
#pragma unroll
  for (int i = 0; i < BIT; ++i) {
    const int p = i * 256 + tid;
    const int r = p >> 3, c = p & 7;
    int brow = n0 + r;
    if (brow > NB - 1) brow = NB - 1;  // clamp partial-N tile staging
    boff[i] = brow * KB + ((c ^ (r & 7)) << 3);
    ldsB[i] = (i * 256 + (tid & ~63)) * 8;
  }

  for (int tm = blockIdx.y; tm * 128 < cnt; tm += gridDim.y) {
    const long m0 = (long)seg_off[e] + (long)tm * 128;
    const u16* Am = A + m0 * (long)lda;

    f32x4 acc[4][NI];
    f32x4 acc2[DUAL ? 4 : 1][DUAL ? NI : 1];
#pragma unroll
    for (int mi = 0; mi < 4; ++mi)
#pragma unroll
      for (int ni = 0; ni < NI; ++ni) {
        acc[mi][ni] = f32x4{0.f, 0.f, 0.f, 0.f};
        if constexpr (DUAL) acc2[mi][ni] = f32x4{0.f, 0.f, 0.f, 0.f};
      }

    for (int k0 = kbeg; k0 < kbeg + kchunk; k0 += 64) {
#pragma unroll
      for (int i = 0; i < AIT; ++i) gload16(Am + aoff[i] + k0, &As[ldsA[i]]);
      if constexpr (DUAL) {
#pragma unroll
        for (int i = 0; i < AIT; ++i)
          gload16(Am + aoff[i] + koffA2 + k0, &Au[ldsA[i]]);
      }
#pragma unroll
      for (int i = 0; i < BIT; ++i) gload16(Be0 + boff[i] + k0, &Bs[ldsB[i]]);
      if constexpr (DUAL) {
#pragma unroll
        for (int i = 0; i < BIT; ++i) gload16(Be1 + boff[i] + k0, &Bu[ldsB[i]]);
      }
      __syncthreads();  // drains vmcnt: LDS writes landed

#pragma unroll
      for (int s = 0; s < 2; ++s) {
        bf16x8 af[4], bfr[NI];
#pragma unroll
        for (int mi = 0; mi < 4; ++mi) {
          const int row = wm * 64 + mi * 16 + fr;
          af[mi] = *(const bf16x8*)&As[(row * 8 + ((s * 4 + g) ^ (row & 7))) * 8];
        }
#pragma unroll
        for (int ni = 0; ni < NI; ++ni) {
          const int row = wn * (NI * 16) + ni * 16 + fr;
          bfr[ni] = *(const bf16x8*)&Bs[(row * 8 + ((s * 4 + g) ^ (row & 7))) * 8];
        }
#pragma unroll
        for (int mi = 0; mi < 4; ++mi)
#pragma unroll
          for (int ni = 0; ni < NI; ++ni)
            acc[mi][ni] = __builtin_amdgcn_mfma_f32_16x16x32_bf16(af[mi], bfr[ni],
                                                                  acc[mi][ni], 0, 0, 0);
        if constexpr (DUAL) {
          bf16x8 au[4], bu[NI];
#pragma unroll
          for (int mi = 0; mi < 4; ++mi) {
            const int row = wm * 64 + mi * 16 + fr;
            au[mi] = *(const bf16x8*)&Au[(row * 8 + ((s * 4 + g) ^ (row & 7))) * 8];
          }
#pragma unroll
          for (int ni = 0; ni < NI; ++ni) {
            const int row = wn * (NI * 16) + ni * 16 + fr;
            bu[ni] = *(const bf16x8*)&Bu[(row * 8 + ((s * 4 + g) ^ (row & 7))) * 8];
          }
#pragma unroll
          for (int mi = 0; mi < 4; ++mi)
#pragma unroll
            for (int ni = 0; ni < NI; ++ni)
              acc2[mi][ni] = __builtin_amdgcn_mfma_f32_16x16x32_bf16(au[mi], bu[ni],
                                                                     acc2[mi][ni], 0, 0, 0);
        }
      }
      __syncthreads();  // WAR: reads done before next stage overwrites
    }

    const int rowlim = cnt - tm * 128;
    const int fcol = lane & 15;
    const int rb = (lane >> 4) << 2;
#pragma unroll
    for (int mi = 0; mi < 4; ++mi) {
#pragma unroll
      for (int ni = 0; ni < NI; ++ni) {
        const int col = n0 + wn * (NI * 16) + ni * 16 + fcol;
#pragma unroll
        for (int j = 0; j < 4; ++j) {
          const int rl = wm * 64 + mi * 16 + rb + j;
          if (rl >= rowlim || col >= NOUT) continue;
          const long grow = m0 + rl;
          const float v = acc[mi][ni][j];
          if constexpr (EPI == 0) {
            out_b[grow * (long)ldo + col] = f2b(v);
          } else if constexpr (EPI == 1) {
            const float u = acc2[mi][ni][j];
            out_b[grow * (long)ldo + col] = f2b(v * u / (1.f + __expf(-v)));
          } else {
            out_f[((long)ks * ROWCAP + grow) * (long)ldo + col] = v;
          }
        }
      }
    }
  }
}

// sum 4 fp32 K-split partials -> bf16
__global__ void k_reduce_cvt(const float* __restrict__ hrf, u16* __restrict__ hrb) {
  constexpr long P = (long)ROWCAP * 320;
  const long d4 = (long)blockIdx.x * 256 + threadIdx.x;
  const float4 a = ((const float4*)hrf)[d4];
  const float4 b = ((const float4*)(hrf + P))[d4];
  const float4 c = ((const float4*)(hrf + 2 * P))[d4];
  const float4 d = ((const float4*)(hrf + 3 * P))[d4];
  ushort4 o;
  o.x = f2b(a.x + b.x + c.x + d.x);
  o.y = f2b(a.y + b.y + c.y + d.y);
  o.z = f2b(a.z + b.z + c.z + d.z);
  o.w = f2b(a.w + b.w + c.w + d.w);
  *(ushort4*)&hrb[d4 * 4] = o;
}

// out[t] = w0*ys[slot0] + w1*ys[slot1]
__global__ void k_combine(const int* __restrict__ inv, const float* __restrict__ rw,
                          const u16* __restrict__ ys, float* __restrict__ out) {
  const int t = blockIdx.x;
  const int g0 = inv[2 * t], g1 = inv[2 * t + 1];
  const float w0 = rw[2 * t], w1 = rw[2 * t + 1];
  const bf16x8* y0 = (const bf16x8*)(ys + (long)g0 * HDIM);
  const bf16x8* y1 = (const bf16x8*)(ys + (long)g1 * HDIM);
  float* o = out + (long)t * HDIM;
#pragma unroll
  for (int j = 0; j < 2; ++j) {
    const int c = threadIdx.x + 256 * j;
    const bf16x8 a = y0[c];
    const bf16x8 b = y1[c];
    float4 r0, r1;
    r0.x = w0 * b2f((u16)a[0]) + w1 * b2f((u16)b[0]);
    r0.y = w0 * b2f((u16)a[1]) + w1 * b2f((u16)b[1]);
    r0.z = w0 * b2f((u16)a[2]) + w1 * b2f((u16)b[2]);
    r0.w = w0 * b2f((u16)a[3]) + w1 * b2f((u16)b[3]);
    r1.x = w0 * b2f((u16)a[4]) + w1 * b2f((u16)b[4]);
    r1.y = w0 * b2f((u16)a[5]) + w1 * b2f((u16)b[5]);
    r1.z = w0 * b2f((u16)a[6]) + w1 * b2f((u16)b[6]);
    r1.w = w0 * b2f((u16)a[7]) + w1 * b2f((u16)b[7]);
    *(float4*)&o[c * 8] = r0;
    *(float4*)&o[c * 8 + 4] = r1;
  }
}

// ---------------- launch ----------------
extern "C" void kernel_launch(void* const* d_in, const int* in_sizes, int n_in,
                              void* d_out, int out_size, void* d_ws, size_t ws_size,
                              hipStream_t stream) {
  const float* x    = (const float*)d_in[0];
  const float* gw   = (const float*)d_in[1];
  const float* w1u  = (const float*)d_in[2];
  const float* w1v  = (const float*)d_in[3];
  const float* w2u  = (const float*)d_in[4];
  const float* w2v  = (const float*)d_in[5];
  const float* w3u  = (const float*)d_in[6];
  const float* w3v  = (const float*)d_in[7];
  const float* u1   = (const float*)d_in[8];
  const float* v1   = (const float*)d_in[9];
  const float* u2   = (const float*)d_in[10];
  const float* v2   = (const float*)d_in[11];
  const float* u3   = (const float*)d_in[12];
  const float* v3   = (const float*)d_in[13];

  float* out_final  = (float*)d_out;                     // [T, H] fp32
  float* out_logits = out_final + (size_t)T_TOK * HDIM;  // [T, E] fp32

  char* W = (char*)d_ws;
  size_t o = 0;
  auto alloc = [&](size_t bytes) {
    size_t r = o;
    o = (o + bytes + 255) & ~(size_t)255;
    return r;
  };
  int*   counts  = (int*)(W + alloc(8 * 4));
  int*   cursors = (int*)(W + alloc(8 * 4));
  int*   seg_off = (int*)(W + alloc(16 * 4));
  int*   sel     = (int*)(W + alloc((size_t)2 * T_TOK * 4));
  float* rw      = (float*)(W + alloc((size_t)2 * T_TOK * 4));
  int*   inv     = (int*)(W + alloc((size_t)2 * T_TOK * 4));
  int*   tok_idx = (int*)(W + alloc((size_t)ROWCAP * 4));
  float* tok_w   = (float*)(W + alloc((size_t)ROWCAP * 4));
  u16* WA = (u16*)(W + alloc((size_t)NE * 640 * HDIM * 2));
  u16* WB = (u16*)(W + alloc((size_t)2 * NE * IDIM * 320 * 2));
  u16* WC = (u16*)(W + alloc((size_t)NE * 320 * IDIM * 2));
  u16* WD = (u16*)(W + alloc((size_t)NE * HDIM * 320 * 2));
  u16* xg = (u16*)(W + alloc((size_t)ROWCAP * HDIM * 2));
  u16* xr = (u16*)(W + alloc((size_t)ROWCAP * 640 * 2));
  u16* hb = (u16*)(W + alloc((size_t)ROWCAP * IDIM * 2));
  u16* hrb = (u16*)(W + alloc((size_t)ROWCAP * 320 * 2));
  // hrf (4 fp32 K-split partials) aliases WB: WB is dead after stage B, hrf
  // written in stage C. ys (stage D bf16 out) aliases xg: dead after stage A.
  float* hrf = (float*)WB;  // needs 4*ROWCAP*320*4 = 42.6MB < WB's 146.8MB
  u16*   ys  = xg;          // ROWCAP*HDIM bf16, exact same extent
  (void)ws_size; (void)in_sizes; (void)n_in; (void)out_size;

  hipMemsetAsync(counts, 0, 8 * 4, stream);

  k_router<<<T_TOK, 64, 0, stream>>>(x, gw, out_logits, counts, sel, rw);
  k_offsets<<<1, 64, 0, stream>>>(counts, seg_off, cursors);
  k_scatter<<<T_TOK / 256, 256, 0, stream>>>(sel, rw, seg_off, cursors, tok_idx, tok_w, inv);

  k_convWA<<<dim3(640, 8), 256, 0, stream>>>(w1v, v1, w3v, v3, WA);
  k_convWB<<<dim3(IDIM / 4, 16), 256, 0, stream>>>(w1u, u1, w3u, u3, WB);
  k_convWC<<<dim3(320, 8), 256, 0, stream>>>(w2v, v2, WC);
  k_convWD<<<dim3(HDIM / 4, 8), 256, 0, stream>>>(w2u, u2, WD);
  k_gather<<<8192, 256, 0, stream>>>(x, tok_idx, xg);

  // Stage A: xr[rows,640] = xg @ WA^T      (K=4096)
  k_gemm<4, false, 0, 1><<<dim3(5, 8, 8), 256, 0, stream>>>(
      xg, HDIM, 0, WA, WA, (long)640 * HDIM, 640, HDIM,
      xr, (float*)0, 640, 640, seg_off, counts);

  // Stage B: hb = silu(xr@W1^T) * (xr@W3^T)   (dual K=320)
  k_gemm<2, true, 1, 1><<<dim3(IDIM / 64, 8, 8), 256, 0, stream>>>(
      xr, 640, 320, WB, WB + (size_t)NE * IDIM * 320, (long)IDIM * 320, IDIM, 320,
      hb, (float*)0, IDIM, IDIM, seg_off, counts);

  // Stage C: hrf[ks] = hb @ WC^T partials   (K=14336 split 4)
  k_gemm<4, false, 2, 4><<<dim3(3, 8, 32), 256, 0, stream>>>(
      hb, IDIM, 0, WC, WC, (long)320 * IDIM, 320, IDIM,
      (u16*)0, hrf, 320, 320, seg_off, counts);

  k_reduce_cvt<<<(ROWCAP * 320 / 4) / 256, 256, 0, stream>>>(hrf, hrb);

  // Stage D: ys[rows,4096] = hr @ WD^T      (K=320)
  k_gemm<4, false, 0, 1><<<dim3(HDIM / 128, 8, 8), 256, 0, stream>>>(
      hrb, 320, 0, WD, WD, (long)HDIM * 320, HDIM, 320,
      ys, (float*)0, HDIM, HDIM, seg_off, counts);

  k_combine<<<T_TOK, 256, 0, stream>>>(inv, rw, ys, out_final);
}